// Round 4
// baseline (754.192 us; speedup 1.0000x reference)
//
#include <hip/hip_runtime.h>
#include <hip/hip_bf16.h>
#include <math.h>

#define NN 100000      // nodes
#define EE 1600000     // edges
#define DH 128         // hidden dim
#define DO 40          // out dim
#define SCAN_NB ((NN + 1023) / 1024)   // 98 scan blocks

// ---------------------------------------------------------------------------
// Edge-index dtype detection. The harness doc says integer inputs arrive as
// int32, but the reference dtype is int64 — detect at runtime to be immune.
// Interpret the first 4096 entries as int64: genuine int64 edge data is all
// in [0, NN); int32 data read as int64 pairs words -> huge values (p~1e-5
// per sample of a false "valid", over 4096 samples => certain detection).
// ---------------------------------------------------------------------------
__global__ void k_detect(const long long* __restrict__ e64, int* __restrict__ flag) {
    __shared__ int sbad;
    if (threadIdx.x == 0) sbad = 0;
    __syncthreads();
    int bad = 0;
    for (int i = threadIdx.x; i < 4096; i += 256) {
        long long v = e64[i];
        if (v < 0 || v >= NN) bad = 1;
    }
    if (__any(bad) && (threadIdx.x & 63) == 0) sbad = 1;
    __syncthreads();
    if (threadIdx.x == 0) flag[0] = sbad ? 0 : 1;   // 1 => int64 layout
}

__device__ __forceinline__ int edge_at(const int* ei32, const long long* ei64,
                                       int is64, size_t idx) {
    return is64 ? (int)ei64[idx] : ei32[idx];
}

// ---------------------------------------------------------------------------
// CSR build: degree histogram -> exclusive scan -> scatter
// ---------------------------------------------------------------------------
__global__ void k_deg(const int* __restrict__ ei32, const long long* __restrict__ ei64,
                      const int* __restrict__ flag, int* __restrict__ deg) {
    int is64 = flag[0];                  // wave-uniform scalar load
    int e = blockIdx.x * 256 + threadIdx.x;
    if (e < EE) {
        int d = edge_at(ei32, ei64, is64, (size_t)EE + e);   // dst
        if (d >= 0 && d < NN)            // defensive: never scatter wild
            atomicAdd(&deg[d], 1);
    }
}

__global__ void k_scan_part(const int* __restrict__ deg, int* __restrict__ bsum) {
    int tid = threadIdx.x;
    int base = blockIdx.x * 1024;
    int s = 0;
    #pragma unroll
    for (int i = 0; i < 4; ++i) {
        int idx = base + i * 256 + tid;
        if (idx < NN) s += deg[idx];
    }
    #pragma unroll
    for (int off = 32; off > 0; off >>= 1) s += __shfl_down(s, off, 64);
    __shared__ int ws[4];
    int lane = tid & 63, w = tid >> 6;
    if (lane == 0) ws[w] = s;
    __syncthreads();
    if (tid == 0) bsum[blockIdx.x] = ws[0] + ws[1] + ws[2] + ws[3];
}

__global__ void k_scan_mid(int* __restrict__ bsum, int* __restrict__ rowptr) {
    int run = 0;
    for (int i = 0; i < SCAN_NB; ++i) { int t = bsum[i]; bsum[i] = run; run += t; }
    rowptr[NN] = run;
}

__global__ void k_scan_fin(const int* __restrict__ deg, const int* __restrict__ bsum,
                           int* __restrict__ rowptr) {
    int tid = threadIdx.x;
    int base = blockIdx.x * 1024 + tid * 4;
    int v[4];
    #pragma unroll
    for (int j = 0; j < 4; ++j) v[j] = (base + j < NN) ? deg[base + j] : 0;
    int tsum = v[0] + v[1] + v[2] + v[3];
    int lane = tid & 63, w = tid >> 6;
    int incl = tsum;
    #pragma unroll
    for (int off = 1; off < 64; off <<= 1) {
        int t = __shfl_up(incl, off, 64);
        if (lane >= off) incl += t;
    }
    __shared__ int wsum[4];
    __shared__ int woff[4];
    if (lane == 63) wsum[w] = incl;
    __syncthreads();
    if (tid == 0) {
        int r = 0;
        #pragma unroll
        for (int i = 0; i < 4; ++i) { int t = wsum[i]; woff[i] = r; r += t; }
    }
    __syncthreads();
    int run = incl - tsum + woff[w] + bsum[blockIdx.x];
    #pragma unroll
    for (int j = 0; j < 4; ++j) {
        if (base + j < NN) rowptr[base + j] = run;
        run += v[j];
    }
}

__global__ void k_scatter(const int* __restrict__ ei32, const long long* __restrict__ ei64,
                          const int* __restrict__ flag, const float* __restrict__ ew,
                          int* __restrict__ cursor, int* __restrict__ col,
                          float* __restrict__ wgt) {
    int is64 = flag[0];
    int e = blockIdx.x * 256 + threadIdx.x;
    if (e < EE) {
        int s = edge_at(ei32, ei64, is64, (size_t)e);
        int d = edge_at(ei32, ei64, is64, (size_t)EE + e);
        if (d < 0 || d >= NN) return;     // defensive
        int pos = atomicAdd(&cursor[d], 1);
        if (pos < 0 || pos >= EE) return; // defensive
        col[pos] = (s >= 0 && s < NN) ? s : 0;
        wgt[pos] = ew[e];
    }
}

// ---------------------------------------------------------------------------
// GEMM  [N,128] x [128,128] -> [N,128]  (fp32 vector; W + x-tile in LDS)
// block 256 threads, 64 rows (2 passes of 32), thread = 4 rows x 4 cols
// ---------------------------------------------------------------------------
__global__ __launch_bounds__(256, 2) void k_gemm128(const float* __restrict__ X,
                                                    const float* __restrict__ W,
                                                    float* __restrict__ out) {
    __shared__ float Wlds[128 * 128];   // 64 KB
    __shared__ float xs[32 * 128];      // 16 KB
    int tid = threadIdx.x;
    const float4* W4 = (const float4*)W;
    float4* Wl4 = (float4*)Wlds;
    #pragma unroll
    for (int i = 0; i < 16; ++i) Wl4[tid + i * 256] = W4[tid + i * 256];

    int cg = tid & 31;   // cols cg*4 .. cg*4+3
    int rh = tid >> 5;   // row slot 0..7 (4 rows each)

    for (int pass = 0; pass < 2; ++pass) {
        int rbase = blockIdx.x * 64 + pass * 32;
        if (rbase >= NN) break;                       // uniform (NN%32==0)
        __syncthreads();
        const float4* X4 = (const float4*)(X + (size_t)rbase * 128);
        float4* xs4 = (float4*)xs;
        #pragma unroll
        for (int i = 0; i < 4; ++i) xs4[tid + i * 256] = X4[tid + i * 256];
        __syncthreads();

        float acc[4][4];
        #pragma unroll
        for (int j = 0; j < 4; ++j)
            #pragma unroll
            for (int q = 0; q < 4; ++q) acc[j][q] = 0.0f;

        const float4* Wl4c = (const float4*)Wlds;
        #pragma unroll 8
        for (int k = 0; k < 128; ++k) {
            float4 wv = Wl4c[k * 32 + cg];
            #pragma unroll
            for (int j = 0; j < 4; ++j) {
                float xk = xs[(rh * 4 + j) * 128 + k];
                acc[j][0] += xk * wv.x;
                acc[j][1] += xk * wv.y;
                acc[j][2] += xk * wv.z;
                acc[j][3] += xk * wv.w;
            }
        }
        #pragma unroll
        for (int j = 0; j < 4; ++j) {
            int row = rbase + rh * 4 + j;
            float4 st = make_float4(acc[j][0], acc[j][1], acc[j][2], acc[j][3]);
            ((float4*)(out + (size_t)row * 128))[cg] = st;
        }
    }
}

// ---------------------------------------------------------------------------
// GEMM  [N,128] x [128,40] -> [N,40]
// ---------------------------------------------------------------------------
__global__ __launch_bounds__(256) void k_gemm40(const float* __restrict__ X,
                                                const float* __restrict__ W,
                                                float* __restrict__ out) {
    __shared__ float Wlds[128 * 40];    // 20 KB
    int tid = threadIdx.x;
    const float4* W4 = (const float4*)W;
    float4* Wl4 = (float4*)Wlds;
    #pragma unroll
    for (int i = 0; i < 5; ++i) Wl4[tid + i * 256] = W4[tid + i * 256];
    __syncthreads();

    int lane = tid & 63;
    int wv = tid >> 6;
    int r8 = lane >> 3;
    int cq = lane & 7;
    int row = blockIdx.x * 32 + wv * 8 + r8;   // NN % 32 == 0
    const float4* x4 = (const float4*)(X + (size_t)row * 128);

    float acc[5] = {0, 0, 0, 0, 0};
    #pragma unroll 4
    for (int k4 = 0; k4 < 32; ++k4) {
        float4 xv = x4[k4];
        float xk[4] = {xv.x, xv.y, xv.z, xv.w};
        #pragma unroll
        for (int kk = 0; kk < 4; ++kk) {
            int k = k4 * 4 + kk;
            #pragma unroll
            for (int j = 0; j < 5; ++j)
                acc[j] += xk[kk] * Wlds[k * 40 + cq * 5 + j];
        }
    }
    #pragma unroll
    for (int j = 0; j < 5; ++j) out[(size_t)row * 40 + cq * 5 + j] = acc[j];
}

// ---------------------------------------------------------------------------
// CSR pull aggregation, D=128: one wave per destination node, float2 per lane.
// 4-edge batch: 4 independent row-gathers in flight per lane (MLP for the
// ~200cyc L2/L3 gather latency), then 2-edge and 1-edge tails.
// ---------------------------------------------------------------------------
__global__ __launch_bounds__(256) void k_agg128(const float* __restrict__ h,
                                                const int* __restrict__ rowptr,
                                                const int* __restrict__ col,
                                                const float* __restrict__ wgt,
                                                const float* __restrict__ bias,
                                                float* __restrict__ out) {
    int node = (blockIdx.x * 256 + threadIdx.x) >> 6;
    if (node >= NN) return;
    int lane = threadIdx.x & 63;
    int beg = rowptr[node], end = rowptr[node + 1];
    float2 acc = make_float2(0.f, 0.f);
    int e = beg;
    for (; e + 3 < end; e += 4) {
        int s0 = col[e],     s1 = col[e + 1];
        int s2 = col[e + 2], s3 = col[e + 3];
        float w0 = wgt[e],     w1 = wgt[e + 1];
        float w2 = wgt[e + 2], w3 = wgt[e + 3];
        float2 v0 = *((const float2*)(h + (size_t)s0 * 128) + lane);
        float2 v1 = *((const float2*)(h + (size_t)s1 * 128) + lane);
        float2 v2 = *((const float2*)(h + (size_t)s2 * 128) + lane);
        float2 v3 = *((const float2*)(h + (size_t)s3 * 128) + lane);
        acc.x += w0 * v0.x + w1 * v1.x + w2 * v2.x + w3 * v3.x;
        acc.y += w0 * v0.y + w1 * v1.y + w2 * v2.y + w3 * v3.y;
    }
    if (e + 1 < end) {
        int s0 = col[e], s1 = col[e + 1];
        float w0 = wgt[e], w1 = wgt[e + 1];
        float2 v0 = *((const float2*)(h + (size_t)s0 * 128) + lane);
        float2 v1 = *((const float2*)(h + (size_t)s1 * 128) + lane);
        acc.x += w0 * v0.x + w1 * v1.x;
        acc.y += w0 * v0.y + w1 * v1.y;
        e += 2;
    }
    if (e < end) {
        int s0 = col[e];
        float w0 = wgt[e];
        float2 v0 = *((const float2*)(h + (size_t)s0 * 128) + lane);
        acc.x += w0 * v0.x;
        acc.y += w0 * v0.y;
    }
    float2 b = ((const float2*)bias)[lane];
    acc.x = fmaxf(acc.x + b.x, 0.f);
    acc.y = fmaxf(acc.y + b.y, 0.f);
    *((float2*)(out + (size_t)node * 128) + lane) = acc;
}

// ---------------------------------------------------------------------------
// CSR pull aggregation D=40 + bias + log_softmax, fused. One wave per node.
// ---------------------------------------------------------------------------
__global__ __launch_bounds__(256) void k_agg40_lsm(const float* __restrict__ h,
                                                   const int* __restrict__ rowptr,
                                                   const int* __restrict__ col,
                                                   const float* __restrict__ wgt,
                                                   const float* __restrict__ bias,
                                                   float* __restrict__ out) {
    int node = (blockIdx.x * 256 + threadIdx.x) >> 6;
    if (node >= NN) return;
    int lane = threadIdx.x & 63;
    bool act = lane < DO;
    int beg = rowptr[node], end = rowptr[node + 1];
    float acc = 0.f;
    int e = beg;
    for (; e + 1 < end; e += 2) {
        int s0 = col[e], s1 = col[e + 1];
        float w0 = wgt[e], w1 = wgt[e + 1];
        float v0 = act ? h[(size_t)s0 * DO + lane] : 0.f;
        float v1 = act ? h[(size_t)s1 * DO + lane] : 0.f;
        acc += w0 * v0 + w1 * v1;
    }
    if (e < end) {
        float v0 = act ? h[(size_t)col[e] * DO + lane] : 0.f;
        acc += wgt[e] * v0;
    }
    acc += act ? bias[lane] : 0.f;

    float m = act ? acc : -INFINITY;
    #pragma unroll
    for (int off = 32; off > 0; off >>= 1) m = fmaxf(m, __shfl_xor(m, off, 64));
    float ex = act ? expf(acc - m) : 0.f;
    float s = ex;
    #pragma unroll
    for (int off = 32; off > 0; off >>= 1) s += __shfl_xor(s, off, 64);
    float res = acc - m - logf(s);
    if (act) out[(size_t)node * DO + lane] = res;
}

// ---------------------------------------------------------------------------
static inline size_t align_up(size_t x, size_t a) { return (x + a - 1) & ~(a - 1); }

extern "C" void kernel_launch(void* const* d_in, const int* in_sizes, int n_in,
                              void* d_out, int out_size, void* d_ws, size_t ws_size,
                              hipStream_t stream) {
    const float*     x    = (const float*)d_in[0];
    const int*       ei32 = (const int*)d_in[1];
    const long long* ei64 = (const long long*)d_in[1];
    const float*     ew   = (const float*)d_in[2];
    const float*     W1   = (const float*)d_in[3];
    const float*     b1   = (const float*)d_in[4];
    const float*     W2   = (const float*)d_in[5];
    const float*     b2   = (const float*)d_in[6];
    const float*     W3   = (const float*)d_in[7];
    const float*     b3   = (const float*)d_in[8];
    float* out = (float*)d_out;

    char* ws = (char*)d_ws;
    size_t off = 0;
    auto alloc = [&](size_t bytes) { size_t o = off; off = align_up(off + bytes, 256); return o; };
    int*   rowptr = (int*)(ws + alloc((size_t)(NN + 1) * 4));
    int*   cursor = (int*)(ws + alloc((size_t)NN * 4));
    int*   deg    = (int*)(ws + alloc((size_t)NN * 4));
    int*   bsum   = (int*)(ws + alloc(4096));
    int*   eflag  = (int*)(ws + alloc(256));
    int*   col    = (int*)(ws + alloc((size_t)EE * 4));
    float* wgt    = (float*)(ws + alloc((size_t)EE * 4));
    float* buf0   = (float*)(ws + alloc((size_t)NN * DH * 4));
    float* buf1   = (float*)(ws + alloc((size_t)NN * DH * 4));
    (void)ws_size;

    // ---- CSR build (every call; ws is re-poisoned each launch) ----
    k_detect<<<1, 256, 0, stream>>>(ei64, eflag);
    hipMemsetAsync(deg, 0, (size_t)NN * 4, stream);
    k_deg<<<EE / 256, 256, 0, stream>>>(ei32, ei64, eflag, deg);
    k_scan_part<<<SCAN_NB, 256, 0, stream>>>(deg, bsum);
    k_scan_mid<<<1, 1, 0, stream>>>(bsum, rowptr);
    k_scan_fin<<<SCAN_NB, 256, 0, stream>>>(deg, bsum, rowptr);
    hipMemcpyAsync(cursor, rowptr, (size_t)NN * 4, hipMemcpyDeviceToDevice, stream);
    k_scatter<<<EE / 256, 256, 0, stream>>>(ei32, ei64, eflag, ew, cursor, col, wgt);

    // ---- layer 1 ----
    k_gemm128<<<(NN + 63) / 64, 256, 0, stream>>>(x, W1, buf0);
    k_agg128<<<NN / 4, 256, 0, stream>>>(buf0, rowptr, col, wgt, b1, buf1);
    // ---- layer 2 ----
    k_gemm128<<<(NN + 63) / 64, 256, 0, stream>>>(buf1, W2, buf0);
    k_agg128<<<NN / 4, 256, 0, stream>>>(buf0, rowptr, col, wgt, b2, buf1);
    // ---- layer 3 + log_softmax ----
    k_gemm40<<<NN / 32, 256, 0, stream>>>(buf1, W3, buf0);
    k_agg40_lsm<<<NN / 4, 256, 0, stream>>>(buf0, rowptr, col, wgt, b3, out);
}

// Round 7
// 730.274 us; speedup vs baseline: 1.0328x; 1.0328x over previous
//
#include <hip/hip_runtime.h>
#include <hip/hip_bf16.h>
#include <math.h>

#define NN 100000      // nodes
#define EE 1600000     // edges
#define DH 128         // hidden dim
#define DO 40          // out dim
#define SCAN_NB ((NN + 1023) / 1024)   // 98 scan blocks

// ---------------------------------------------------------------------------
// Edge-index dtype detection (immune to int32-vs-int64 delivery).
// ---------------------------------------------------------------------------
__global__ void k_detect(const long long* __restrict__ e64, int* __restrict__ flag) {
    __shared__ int sbad;
    if (threadIdx.x == 0) sbad = 0;
    __syncthreads();
    int bad = 0;
    for (int i = threadIdx.x; i < 4096; i += 256) {
        long long v = e64[i];
        if (v < 0 || v >= NN) bad = 1;
    }
    if (__any(bad) && (threadIdx.x & 63) == 0) sbad = 1;
    __syncthreads();
    if (threadIdx.x == 0) flag[0] = sbad ? 0 : 1;   // 1 => int64 layout
}

__device__ __forceinline__ int edge_at(const int* ei32, const long long* ei64,
                                       int is64, size_t idx) {
    return is64 ? (int)ei64[idx] : ei32[idx];
}

// ---------------------------------------------------------------------------
// CSR build: degree histogram -> exclusive scan -> scatter
// ---------------------------------------------------------------------------
__global__ void k_deg(const int* __restrict__ ei32, const long long* __restrict__ ei64,
                      const int* __restrict__ flag, int* __restrict__ deg) {
    int is64 = flag[0];
    int e = blockIdx.x * 256 + threadIdx.x;
    if (e < EE) {
        int d = edge_at(ei32, ei64, is64, (size_t)EE + e);
        if (d >= 0 && d < NN)
            atomicAdd(&deg[d], 1);
    }
}

__global__ void k_scan_part(const int* __restrict__ deg, int* __restrict__ bsum) {
    int tid = threadIdx.x;
    int base = blockIdx.x * 1024;
    int s = 0;
    #pragma unroll
    for (int i = 0; i < 4; ++i) {
        int idx = base + i * 256 + tid;
        if (idx < NN) s += deg[idx];
    }
    #pragma unroll
    for (int off = 32; off > 0; off >>= 1) s += __shfl_down(s, off, 64);
    __shared__ int ws[4];
    int lane = tid & 63, w = tid >> 6;
    if (lane == 0) ws[w] = s;
    __syncthreads();
    if (tid == 0) bsum[blockIdx.x] = ws[0] + ws[1] + ws[2] + ws[3];
}

// parallel 98-element exclusive scan (was: single-thread serial loop)
__global__ void k_scan_mid(int* __restrict__ bsum, int* __restrict__ rowptr) {
    int tid = threadIdx.x;                  // 128 threads
    int v = (tid < SCAN_NB) ? bsum[tid] : 0;
    int lane = tid & 63, w = tid >> 6;
    int incl = v;
    #pragma unroll
    for (int off = 1; off < 64; off <<= 1) {
        int t = __shfl_up(incl, off, 64);
        if (lane >= off) incl += t;
    }
    __shared__ int ws[2];
    if (lane == 63) ws[w] = incl;
    __syncthreads();
    if (w == 1) incl += ws[0];
    if (tid < SCAN_NB) bsum[tid] = incl - v;          // exclusive
    if (tid == SCAN_NB - 1) rowptr[NN] = incl;        // total == EE
}

__global__ void k_scan_fin(const int* __restrict__ deg, const int* __restrict__ bsum,
                           int* __restrict__ rowptr) {
    int tid = threadIdx.x;
    int base = blockIdx.x * 1024 + tid * 4;
    int v[4];
    #pragma unroll
    for (int j = 0; j < 4; ++j) v[j] = (base + j < NN) ? deg[base + j] : 0;
    int tsum = v[0] + v[1] + v[2] + v[3];
    int lane = tid & 63, w = tid >> 6;
    int incl = tsum;
    #pragma unroll
    for (int off = 1; off < 64; off <<= 1) {
        int t = __shfl_up(incl, off, 64);
        if (lane >= off) incl += t;
    }
    __shared__ int wsum[4];
    __shared__ int woff[4];
    if (lane == 63) wsum[w] = incl;
    __syncthreads();
    if (tid == 0) {
        int r = 0;
        #pragma unroll
        for (int i = 0; i < 4; ++i) { int t = wsum[i]; woff[i] = r; r += t; }
    }
    __syncthreads();
    int run = incl - tsum + woff[w] + bsum[blockIdx.x];
    #pragma unroll
    for (int j = 0; j < 4; ++j) {
        if (base + j < NN) rowptr[base + j] = run;
        run += v[j];
    }
}

__global__ void k_scatter(const int* __restrict__ ei32, const long long* __restrict__ ei64,
                          const int* __restrict__ flag, const float* __restrict__ ew,
                          int* __restrict__ cursor, int* __restrict__ col,
                          float* __restrict__ wgt) {
    int is64 = flag[0];
    int e = blockIdx.x * 256 + threadIdx.x;
    if (e < EE) {
        int s = edge_at(ei32, ei64, is64, (size_t)e);
        int d = edge_at(ei32, ei64, is64, (size_t)EE + e);
        if (d < 0 || d >= NN) return;
        int pos = atomicAdd(&cursor[d], 1);
        if (pos < 0 || pos >= EE) return;
        col[pos] = (s >= 0 && s < NN) ? s : 0;
        wgt[pos] = ew[e];
    }
}

// ---------------------------------------------------------------------------
// GEMM  [N,128] x [128,128] -> [N,128]  (fp32 vector; W + x-tile in LDS)
// ---------------------------------------------------------------------------
__global__ __launch_bounds__(256, 2) void k_gemm128(const float* __restrict__ X,
                                                    const float* __restrict__ W,
                                                    float* __restrict__ out) {
    __shared__ float Wlds[128 * 128];   // 64 KB
    __shared__ float xs[32 * 128];      // 16 KB
    int tid = threadIdx.x;
    const float4* W4 = (const float4*)W;
    float4* Wl4 = (float4*)Wlds;
    #pragma unroll
    for (int i = 0; i < 16; ++i) Wl4[tid + i * 256] = W4[tid + i * 256];

    int cg = tid & 31;
    int rh = tid >> 5;

    for (int pass = 0; pass < 2; ++pass) {
        int rbase = blockIdx.x * 64 + pass * 32;
        if (rbase >= NN) break;
        __syncthreads();
        const float4* X4 = (const float4*)(X + (size_t)rbase * 128);
        float4* xs4 = (float4*)xs;
        #pragma unroll
        for (int i = 0; i < 4; ++i) xs4[tid + i * 256] = X4[tid + i * 256];
        __syncthreads();

        float acc[4][4];
        #pragma unroll
        for (int j = 0; j < 4; ++j)
            #pragma unroll
            for (int q = 0; q < 4; ++q) acc[j][q] = 0.0f;

        const float4* Wl4c = (const float4*)Wlds;
        #pragma unroll 8
        for (int k = 0; k < 128; ++k) {
            float4 wv = Wl4c[k * 32 + cg];
            #pragma unroll
            for (int j = 0; j < 4; ++j) {
                float xk = xs[(rh * 4 + j) * 128 + k];
                acc[j][0] += xk * wv.x;
                acc[j][1] += xk * wv.y;
                acc[j][2] += xk * wv.z;
                acc[j][3] += xk * wv.w;
            }
        }
        #pragma unroll
        for (int j = 0; j < 4; ++j) {
            int row = rbase + rh * 4 + j;
            float4 st = make_float4(acc[j][0], acc[j][1], acc[j][2], acc[j][3]);
            ((float4*)(out + (size_t)row * 128))[cg] = st;
        }
    }
}

// ---------------------------------------------------------------------------
// GEMM  [N,128] x [128,40] -> [N,40]
// ---------------------------------------------------------------------------
__global__ __launch_bounds__(256) void k_gemm40(const float* __restrict__ X,
                                                const float* __restrict__ W,
                                                float* __restrict__ out) {
    __shared__ float Wlds[128 * 40];    // 20 KB
    int tid = threadIdx.x;
    const float4* W4 = (const float4*)W;
    float4* Wl4 = (float4*)Wlds;
    #pragma unroll
    for (int i = 0; i < 5; ++i) Wl4[tid + i * 256] = W4[tid + i * 256];
    __syncthreads();

    int lane = tid & 63;
    int wv = tid >> 6;
    int r8 = lane >> 3;
    int cq = lane & 7;
    int row = blockIdx.x * 32 + wv * 8 + r8;   // NN % 32 == 0
    const float4* x4 = (const float4*)(X + (size_t)row * 128);

    float acc[5] = {0, 0, 0, 0, 0};
    #pragma unroll 4
    for (int k4 = 0; k4 < 32; ++k4) {
        float4 xv = x4[k4];
        float xk[4] = {xv.x, xv.y, xv.z, xv.w};
        #pragma unroll
        for (int kk = 0; kk < 4; ++kk) {
            int k = k4 * 4 + kk;
            #pragma unroll
            for (int j = 0; j < 5; ++j)
                acc[j] += xk[kk] * Wlds[k * 40 + cq * 5 + j];
        }
    }
    #pragma unroll
    for (int j = 0; j < 5; ++j) out[(size_t)row * 40 + cq * 5 + j] = acc[j];
}

// ---------------------------------------------------------------------------
// CSR pull aggregation, D=128: 32 lanes per node (2 nodes/wave), float4/lane.
// 4-edge batch => 4 x 16B gathers in flight per lane (vs 4 x 8B before):
// double the bytes in flight, half the iterations. Latency-bound fix (G7).
// ---------------------------------------------------------------------------
__global__ __launch_bounds__(256) void k_agg128(const float* __restrict__ h,
                                                const int* __restrict__ rowptr,
                                                const int* __restrict__ col,
                                                const float* __restrict__ wgt,
                                                const float* __restrict__ bias,
                                                float* __restrict__ out) {
    int node = (blockIdx.x * 256 + threadIdx.x) >> 5;   // 32-lane group per node
    if (node >= NN) return;
    int lane = threadIdx.x & 31;                        // float4 slot within row
    int beg = rowptr[node], end = rowptr[node + 1];
    float4 acc = make_float4(0.f, 0.f, 0.f, 0.f);
    int e = beg;
    for (; e + 3 < end; e += 4) {
        int s0 = col[e],     s1 = col[e + 1];
        int s2 = col[e + 2], s3 = col[e + 3];
        float w0 = wgt[e],     w1 = wgt[e + 1];
        float w2 = wgt[e + 2], w3 = wgt[e + 3];
        float4 v0 = *((const float4*)(h + (size_t)s0 * 128) + lane);
        float4 v1 = *((const float4*)(h + (size_t)s1 * 128) + lane);
        float4 v2 = *((const float4*)(h + (size_t)s2 * 128) + lane);
        float4 v3 = *((const float4*)(h + (size_t)s3 * 128) + lane);
        acc.x += w0 * v0.x + w1 * v1.x + w2 * v2.x + w3 * v3.x;
        acc.y += w0 * v0.y + w1 * v1.y + w2 * v2.y + w3 * v3.y;
        acc.z += w0 * v0.z + w1 * v1.z + w2 * v2.z + w3 * v3.z;
        acc.w += w0 * v0.w + w1 * v1.w + w2 * v2.w + w3 * v3.w;
    }
    if (e + 1 < end) {
        int s0 = col[e], s1 = col[e + 1];
        float w0 = wgt[e], w1 = wgt[e + 1];
        float4 v0 = *((const float4*)(h + (size_t)s0 * 128) + lane);
        float4 v1 = *((const float4*)(h + (size_t)s1 * 128) + lane);
        acc.x += w0 * v0.x + w1 * v1.x;
        acc.y += w0 * v0.y + w1 * v1.y;
        acc.z += w0 * v0.z + w1 * v1.z;
        acc.w += w0 * v0.w + w1 * v1.w;
        e += 2;
    }
    if (e < end) {
        int s0 = col[e];
        float w0 = wgt[e];
        float4 v0 = *((const float4*)(h + (size_t)s0 * 128) + lane);
        acc.x += w0 * v0.x;
        acc.y += w0 * v0.y;
        acc.z += w0 * v0.z;
        acc.w += w0 * v0.w;
    }
    float4 b = ((const float4*)bias)[lane];
    acc.x = fmaxf(acc.x + b.x, 0.f);
    acc.y = fmaxf(acc.y + b.y, 0.f);
    acc.z = fmaxf(acc.z + b.z, 0.f);
    acc.w = fmaxf(acc.w + b.w, 0.f);
    *((float4*)(out + (size_t)node * 128) + lane) = acc;
}

// ---------------------------------------------------------------------------
// CSR pull aggregation D=40 + bias + log_softmax, fused. One wave per node.
// 4-edge batch for memory-level parallelism.
// ---------------------------------------------------------------------------
__global__ __launch_bounds__(256) void k_agg40_lsm(const float* __restrict__ h,
                                                   const int* __restrict__ rowptr,
                                                   const int* __restrict__ col,
                                                   const float* __restrict__ wgt,
                                                   const float* __restrict__ bias,
                                                   float* __restrict__ out) {
    int node = (blockIdx.x * 256 + threadIdx.x) >> 6;
    if (node >= NN) return;
    int lane = threadIdx.x & 63;
    bool act = lane < DO;
    int ln = act ? lane : 0;                 // keep inactive lanes in-bounds
    int beg = rowptr[node], end = rowptr[node + 1];
    float acc = 0.f;
    int e = beg;
    for (; e + 3 < end; e += 4) {
        int s0 = col[e],     s1 = col[e + 1];
        int s2 = col[e + 2], s3 = col[e + 3];
        float w0 = wgt[e],     w1 = wgt[e + 1];
        float w2 = wgt[e + 2], w3 = wgt[e + 3];
        float v0 = h[(size_t)s0 * DO + ln];
        float v1 = h[(size_t)s1 * DO + ln];
        float v2 = h[(size_t)s2 * DO + ln];
        float v3 = h[(size_t)s3 * DO + ln];
        acc += w0 * v0 + w1 * v1 + w2 * v2 + w3 * v3;
    }
    for (; e < end; ++e) {
        acc += wgt[e] * h[(size_t)col[e] * DO + ln];
    }
    acc += bias[ln];

    float m = act ? acc : -INFINITY;
    #pragma unroll
    for (int off = 32; off > 0; off >>= 1) m = fmaxf(m, __shfl_xor(m, off, 64));
    float ex = act ? expf(acc - m) : 0.f;
    float s = ex;
    #pragma unroll
    for (int off = 32; off > 0; off >>= 1) s += __shfl_xor(s, off, 64);
    float res = acc - m - logf(s);
    if (act) out[(size_t)node * DO + lane] = res;
}

// ---------------------------------------------------------------------------
static inline size_t align_up(size_t x, size_t a) { return (x + a - 1) & ~(a - 1); }

extern "C" void kernel_launch(void* const* d_in, const int* in_sizes, int n_in,
                              void* d_out, int out_size, void* d_ws, size_t ws_size,
                              hipStream_t stream) {
    const float*     x    = (const float*)d_in[0];
    const int*       ei32 = (const int*)d_in[1];
    const long long* ei64 = (const long long*)d_in[1];
    const float*     ew   = (const float*)d_in[2];
    const float*     W1   = (const float*)d_in[3];
    const float*     b1   = (const float*)d_in[4];
    const float*     W2   = (const float*)d_in[5];
    const float*     b2   = (const float*)d_in[6];
    const float*     W3   = (const float*)d_in[7];
    const float*     b3   = (const float*)d_in[8];
    float* out = (float*)d_out;

    char* ws = (char*)d_ws;
    size_t off = 0;
    auto alloc = [&](size_t bytes) { size_t o = off; off = align_up(off + bytes, 256); return o; };
    int*   rowptr = (int*)(ws + alloc((size_t)(NN + 1) * 4));
    int*   cursor = (int*)(ws + alloc((size_t)NN * 4));
    int*   deg    = (int*)(ws + alloc((size_t)NN * 4));
    int*   bsum   = (int*)(ws + alloc(4096));
    int*   eflag  = (int*)(ws + alloc(256));
    int*   col    = (int*)(ws + alloc((size_t)EE * 4));
    float* wgt    = (float*)(ws + alloc((size_t)EE * 4));
    float* buf0   = (float*)(ws + alloc((size_t)NN * DH * 4));
    float* buf1   = (float*)(ws + alloc((size_t)NN * DH * 4));
    (void)ws_size;

    // ---- CSR build ----
    k_detect<<<1, 256, 0, stream>>>(ei64, eflag);
    hipMemsetAsync(deg, 0, (size_t)NN * 4, stream);
    k_deg<<<EE / 256, 256, 0, stream>>>(ei32, ei64, eflag, deg);
    k_scan_part<<<SCAN_NB, 256, 0, stream>>>(deg, bsum);
    k_scan_mid<<<1, 128, 0, stream>>>(bsum, rowptr);
    k_scan_fin<<<SCAN_NB, 256, 0, stream>>>(deg, bsum, rowptr);
    hipMemcpyAsync(cursor, rowptr, (size_t)NN * 4, hipMemcpyDeviceToDevice, stream);
    k_scatter<<<EE / 256, 256, 0, stream>>>(ei32, ei64, eflag, ew, cursor, col, wgt);

    // ---- layer 1 ----
    k_gemm128<<<(NN + 63) / 64, 256, 0, stream>>>(x, W1, buf0);
    k_agg128<<<(NN + 7) / 8, 256, 0, stream>>>(buf0, rowptr, col, wgt, b1, buf1);
    // ---- layer 2 ----
    k_gemm128<<<(NN + 63) / 64, 256, 0, stream>>>(buf1, W2, buf0);
    k_agg128<<<(NN + 7) / 8, 256, 0, stream>>>(buf0, rowptr, col, wgt, b2, buf1);
    // ---- layer 3 + log_softmax ----
    k_gemm40<<<NN / 32, 256, 0, stream>>>(buf1, W3, buf0);
    k_agg40_lsm<<<NN / 4, 256, 0, stream>>>(buf0, rowptr, col, wgt, b3, out);
}

// Round 8
// 722.093 us; speedup vs baseline: 1.0445x; 1.0113x over previous
//
#include <hip/hip_runtime.h>
#include <hip/hip_bf16.h>
#include <math.h>

#define NN 100000      // nodes
#define EE 1600000     // edges
#define DH 128         // hidden dim
#define DO 40          // out dim
#define SCAN_NB ((NN + 1023) / 1024)   // 98 scan blocks

// ---------------------------------------------------------------------------
// Edge-index dtype detection (immune to int32-vs-int64 delivery).
// ---------------------------------------------------------------------------
__global__ void k_detect(const long long* __restrict__ e64, int* __restrict__ flag) {
    __shared__ int sbad;
    if (threadIdx.x == 0) sbad = 0;
    __syncthreads();
    int bad = 0;
    for (int i = threadIdx.x; i < 4096; i += 256) {
        long long v = e64[i];
        if (v < 0 || v >= NN) bad = 1;
    }
    if (__any(bad) && (threadIdx.x & 63) == 0) sbad = 1;
    __syncthreads();
    if (threadIdx.x == 0) flag[0] = sbad ? 0 : 1;   // 1 => int64 layout
}

__device__ __forceinline__ int edge_at(const int* ei32, const long long* ei64,
                                       int is64, size_t idx) {
    return is64 ? (int)ei64[idx] : ei32[idx];
}

// ---------------------------------------------------------------------------
// CSR build: degree histogram -> exclusive scan -> scatter
// 4 edges/thread: batch independent atomics for latency overlap.
// ---------------------------------------------------------------------------
__global__ void k_deg(const int* __restrict__ ei32, const long long* __restrict__ ei64,
                      const int* __restrict__ flag, int* __restrict__ deg) {
    int is64 = flag[0];
    int e0 = blockIdx.x * 1024 + threadIdx.x;
    #pragma unroll
    for (int i = 0; i < 4; ++i) {
        int e = e0 + i * 256;
        if (e < EE) {
            int d = edge_at(ei32, ei64, is64, (size_t)EE + e);
            if (d >= 0 && d < NN)
                atomicAdd(&deg[d], 1);
        }
    }
}

__global__ void k_scan_part(const int* __restrict__ deg, int* __restrict__ bsum) {
    int tid = threadIdx.x;
    int base = blockIdx.x * 1024;
    int s = 0;
    #pragma unroll
    for (int i = 0; i < 4; ++i) {
        int idx = base + i * 256 + tid;
        if (idx < NN) s += deg[idx];
    }
    #pragma unroll
    for (int off = 32; off > 0; off >>= 1) s += __shfl_down(s, off, 64);
    __shared__ int ws[4];
    int lane = tid & 63, w = tid >> 6;
    if (lane == 0) ws[w] = s;
    __syncthreads();
    if (tid == 0) bsum[blockIdx.x] = ws[0] + ws[1] + ws[2] + ws[3];
}

// parallel 98-element exclusive scan
__global__ void k_scan_mid(int* __restrict__ bsum, int* __restrict__ rowptr) {
    int tid = threadIdx.x;                  // 128 threads
    int v = (tid < SCAN_NB) ? bsum[tid] : 0;
    int lane = tid & 63, w = tid >> 6;
    int incl = v;
    #pragma unroll
    for (int off = 1; off < 64; off <<= 1) {
        int t = __shfl_up(incl, off, 64);
        if (lane >= off) incl += t;
    }
    __shared__ int ws[2];
    if (lane == 63) ws[w] = incl;
    __syncthreads();
    if (w == 1) incl += ws[0];
    if (tid < SCAN_NB) bsum[tid] = incl - v;          // exclusive
    if (tid == SCAN_NB - 1) rowptr[NN] = incl;        // total == EE
}

__global__ void k_scan_fin(const int* __restrict__ deg, const int* __restrict__ bsum,
                           int* __restrict__ rowptr) {
    int tid = threadIdx.x;
    int base = blockIdx.x * 1024 + tid * 4;
    int v[4];
    #pragma unroll
    for (int j = 0; j < 4; ++j) v[j] = (base + j < NN) ? deg[base + j] : 0;
    int tsum = v[0] + v[1] + v[2] + v[3];
    int lane = tid & 63, w = tid >> 6;
    int incl = tsum;
    #pragma unroll
    for (int off = 1; off < 64; off <<= 1) {
        int t = __shfl_up(incl, off, 64);
        if (lane >= off) incl += t;
    }
    __shared__ int wsum[4];
    __shared__ int woff[4];
    if (lane == 63) wsum[w] = incl;
    __syncthreads();
    if (tid == 0) {
        int r = 0;
        #pragma unroll
        for (int i = 0; i < 4; ++i) { int t = wsum[i]; woff[i] = r; r += t; }
    }
    __syncthreads();
    int run = incl - tsum + woff[w] + bsum[blockIdx.x];
    #pragma unroll
    for (int j = 0; j < 4; ++j) {
        if (base + j < NN) rowptr[base + j] = run;
        run += v[j];
    }
}

// Scatter: 4 edges/thread. Phase 1: load 4 (s,d,w). Phase 2: 4 independent
// returning atomics issued back-to-back (one vmcnt wait covers all).
// Phase 3: 4 packed int2 stores — (src, wgt) in ONE 8B line touch instead
// of two 4B touches in different arrays (halves random-write lines).
__global__ void k_scatter(const int* __restrict__ ei32, const long long* __restrict__ ei64,
                          const int* __restrict__ flag, const float* __restrict__ ew,
                          int* __restrict__ cursor, int2* __restrict__ pack) {
    int is64 = flag[0];
    int e0 = blockIdx.x * 1024 + threadIdx.x;
    int s[4], d[4];
    float w[4];
    bool val[4];
    #pragma unroll
    for (int i = 0; i < 4; ++i) {
        int e = e0 + i * 256;
        val[i] = (e < EE);
        if (val[i]) {
            s[i] = edge_at(ei32, ei64, is64, (size_t)e);
            d[i] = edge_at(ei32, ei64, is64, (size_t)EE + e);
            w[i] = ew[e];
            if (d[i] < 0 || d[i] >= NN) val[i] = false;
        }
    }
    int pos[4];
    #pragma unroll
    for (int i = 0; i < 4; ++i)
        if (val[i]) pos[i] = atomicAdd(&cursor[d[i]], 1);
    #pragma unroll
    for (int i = 0; i < 4; ++i)
        if (val[i] && pos[i] >= 0 && pos[i] < EE) {
            int sc = (s[i] >= 0 && s[i] < NN) ? s[i] : 0;
            pack[pos[i]] = make_int2(sc, __float_as_int(w[i]));
        }
}

// ---------------------------------------------------------------------------
// GEMM  [N,128] x [128,128] -> [N,128]  (fp32 vector; W + x-tile in LDS)
// ---------------------------------------------------------------------------
__global__ __launch_bounds__(256, 2) void k_gemm128(const float* __restrict__ X,
                                                    const float* __restrict__ W,
                                                    float* __restrict__ out) {
    __shared__ float Wlds[128 * 128];   // 64 KB
    __shared__ float xs[32 * 128];      // 16 KB
    int tid = threadIdx.x;
    const float4* W4 = (const float4*)W;
    float4* Wl4 = (float4*)Wlds;
    #pragma unroll
    for (int i = 0; i < 16; ++i) Wl4[tid + i * 256] = W4[tid + i * 256];

    int cg = tid & 31;
    int rh = tid >> 5;

    for (int pass = 0; pass < 2; ++pass) {
        int rbase = blockIdx.x * 64 + pass * 32;
        if (rbase >= NN) break;
        __syncthreads();
        const float4* X4 = (const float4*)(X + (size_t)rbase * 128);
        float4* xs4 = (float4*)xs;
        #pragma unroll
        for (int i = 0; i < 4; ++i) xs4[tid + i * 256] = X4[tid + i * 256];
        __syncthreads();

        float acc[4][4];
        #pragma unroll
        for (int j = 0; j < 4; ++j)
            #pragma unroll
            for (int q = 0; q < 4; ++q) acc[j][q] = 0.0f;

        const float4* Wl4c = (const float4*)Wlds;
        #pragma unroll 8
        for (int k = 0; k < 128; ++k) {
            float4 wv = Wl4c[k * 32 + cg];
            #pragma unroll
            for (int j = 0; j < 4; ++j) {
                float xk = xs[(rh * 4 + j) * 128 + k];
                acc[j][0] += xk * wv.x;
                acc[j][1] += xk * wv.y;
                acc[j][2] += xk * wv.z;
                acc[j][3] += xk * wv.w;
            }
        }
        #pragma unroll
        for (int j = 0; j < 4; ++j) {
            int row = rbase + rh * 4 + j;
            float4 st = make_float4(acc[j][0], acc[j][1], acc[j][2], acc[j][3]);
            ((float4*)(out + (size_t)row * 128))[cg] = st;
        }
    }
}

// ---------------------------------------------------------------------------
// GEMM  [N,128] x [128,40] -> [N,40]
// ---------------------------------------------------------------------------
__global__ __launch_bounds__(256) void k_gemm40(const float* __restrict__ X,
                                                const float* __restrict__ W,
                                                float* __restrict__ out) {
    __shared__ float Wlds[128 * 40];    // 20 KB
    int tid = threadIdx.x;
    const float4* W4 = (const float4*)W;
    float4* Wl4 = (float4*)Wlds;
    #pragma unroll
    for (int i = 0; i < 5; ++i) Wl4[tid + i * 256] = W4[tid + i * 256];
    __syncthreads();

    int lane = tid & 63;
    int wv = tid >> 6;
    int r8 = lane >> 3;
    int cq = lane & 7;
    int row = blockIdx.x * 32 + wv * 8 + r8;   // NN % 32 == 0
    const float4* x4 = (const float4*)(X + (size_t)row * 128);

    float acc[5] = {0, 0, 0, 0, 0};
    #pragma unroll 4
    for (int k4 = 0; k4 < 32; ++k4) {
        float4 xv = x4[k4];
        float xk[4] = {xv.x, xv.y, xv.z, xv.w};
        #pragma unroll
        for (int kk = 0; kk < 4; ++kk) {
            int k = k4 * 4 + kk;
            #pragma unroll
            for (int j = 0; j < 5; ++j)
                acc[j] += xk[kk] * Wlds[k * 40 + cq * 5 + j];
        }
    }
    #pragma unroll
    for (int j = 0; j < 5; ++j) out[(size_t)row * 40 + cq * 5 + j] = acc[j];
}

// ---------------------------------------------------------------------------
// CSR pull aggregation, D=128: 32 lanes per node (2 nodes/wave), float4/lane.
// Packed (src,wgt) edge records: one 8B broadcast load per edge.
// ---------------------------------------------------------------------------
__global__ __launch_bounds__(256) void k_agg128(const float* __restrict__ h,
                                                const int* __restrict__ rowptr,
                                                const int2* __restrict__ pack,
                                                const float* __restrict__ bias,
                                                float* __restrict__ out) {
    int node = (blockIdx.x * 256 + threadIdx.x) >> 5;   // 32-lane group per node
    if (node >= NN) return;
    int lane = threadIdx.x & 31;                        // float4 slot within row
    int beg = rowptr[node], end = rowptr[node + 1];
    float4 acc = make_float4(0.f, 0.f, 0.f, 0.f);
    int e = beg;
    for (; e + 3 < end; e += 4) {
        int2 p0 = pack[e],     p1 = pack[e + 1];
        int2 p2 = pack[e + 2], p3 = pack[e + 3];
        float w0 = __int_as_float(p0.y), w1 = __int_as_float(p1.y);
        float w2 = __int_as_float(p2.y), w3 = __int_as_float(p3.y);
        float4 v0 = *((const float4*)(h + (size_t)p0.x * 128) + lane);
        float4 v1 = *((const float4*)(h + (size_t)p1.x * 128) + lane);
        float4 v2 = *((const float4*)(h + (size_t)p2.x * 128) + lane);
        float4 v3 = *((const float4*)(h + (size_t)p3.x * 128) + lane);
        acc.x += w0 * v0.x + w1 * v1.x + w2 * v2.x + w3 * v3.x;
        acc.y += w0 * v0.y + w1 * v1.y + w2 * v2.y + w3 * v3.y;
        acc.z += w0 * v0.z + w1 * v1.z + w2 * v2.z + w3 * v3.z;
        acc.w += w0 * v0.w + w1 * v1.w + w2 * v2.w + w3 * v3.w;
    }
    if (e + 1 < end) {
        int2 p0 = pack[e], p1 = pack[e + 1];
        float w0 = __int_as_float(p0.y), w1 = __int_as_float(p1.y);
        float4 v0 = *((const float4*)(h + (size_t)p0.x * 128) + lane);
        float4 v1 = *((const float4*)(h + (size_t)p1.x * 128) + lane);
        acc.x += w0 * v0.x + w1 * v1.x;
        acc.y += w0 * v0.y + w1 * v1.y;
        acc.z += w0 * v0.z + w1 * v1.z;
        acc.w += w0 * v0.w + w1 * v1.w;
        e += 2;
    }
    if (e < end) {
        int2 p0 = pack[e];
        float w0 = __int_as_float(p0.y);
        float4 v0 = *((const float4*)(h + (size_t)p0.x * 128) + lane);
        acc.x += w0 * v0.x;
        acc.y += w0 * v0.y;
        acc.z += w0 * v0.z;
        acc.w += w0 * v0.w;
    }
    float4 b = ((const float4*)bias)[lane];
    acc.x = fmaxf(acc.x + b.x, 0.f);
    acc.y = fmaxf(acc.y + b.y, 0.f);
    acc.z = fmaxf(acc.z + b.z, 0.f);
    acc.w = fmaxf(acc.w + b.w, 0.f);
    *((float4*)(out + (size_t)node * 128) + lane) = acc;
}

// ---------------------------------------------------------------------------
// CSR pull aggregation D=40 + bias + log_softmax, fused. One wave per node.
// ---------------------------------------------------------------------------
__global__ __launch_bounds__(256) void k_agg40_lsm(const float* __restrict__ h,
                                                   const int* __restrict__ rowptr,
                                                   const int2* __restrict__ pack,
                                                   const float* __restrict__ bias,
                                                   float* __restrict__ out) {
    int node = (blockIdx.x * 256 + threadIdx.x) >> 6;
    if (node >= NN) return;
    int lane = threadIdx.x & 63;
    bool act = lane < DO;
    int ln = act ? lane : 0;                 // keep inactive lanes in-bounds
    int beg = rowptr[node], end = rowptr[node + 1];
    float acc = 0.f;
    int e = beg;
    for (; e + 3 < end; e += 4) {
        int2 p0 = pack[e],     p1 = pack[e + 1];
        int2 p2 = pack[e + 2], p3 = pack[e + 3];
        float v0 = h[(size_t)p0.x * DO + ln];
        float v1 = h[(size_t)p1.x * DO + ln];
        float v2 = h[(size_t)p2.x * DO + ln];
        float v3 = h[(size_t)p3.x * DO + ln];
        acc += __int_as_float(p0.y) * v0 + __int_as_float(p1.y) * v1
             + __int_as_float(p2.y) * v2 + __int_as_float(p3.y) * v3;
    }
    for (; e < end; ++e) {
        int2 p0 = pack[e];
        acc += __int_as_float(p0.y) * h[(size_t)p0.x * DO + ln];
    }
    acc += bias[ln];

    float m = act ? acc : -INFINITY;
    #pragma unroll
    for (int off = 32; off > 0; off >>= 1) m = fmaxf(m, __shfl_xor(m, off, 64));
    float ex = act ? expf(acc - m) : 0.f;
    float s = ex;
    #pragma unroll
    for (int off = 32; off > 0; off >>= 1) s += __shfl_xor(s, off, 64);
    float res = acc - m - logf(s);
    if (act) out[(size_t)node * DO + lane] = res;
}

// ---------------------------------------------------------------------------
static inline size_t align_up(size_t x, size_t a) { return (x + a - 1) & ~(a - 1); }

extern "C" void kernel_launch(void* const* d_in, const int* in_sizes, int n_in,
                              void* d_out, int out_size, void* d_ws, size_t ws_size,
                              hipStream_t stream) {
    const float*     x    = (const float*)d_in[0];
    const int*       ei32 = (const int*)d_in[1];
    const long long* ei64 = (const long long*)d_in[1];
    const float*     ew   = (const float*)d_in[2];
    const float*     W1   = (const float*)d_in[3];
    const float*     b1   = (const float*)d_in[4];
    const float*     W2   = (const float*)d_in[5];
    const float*     b2   = (const float*)d_in[6];
    const float*     W3   = (const float*)d_in[7];
    const float*     b3   = (const float*)d_in[8];
    float* out = (float*)d_out;

    char* ws = (char*)d_ws;
    size_t off = 0;
    auto alloc = [&](size_t bytes) { size_t o = off; off = align_up(off + bytes, 256); return o; };
    int*   rowptr = (int*)(ws + alloc((size_t)(NN + 1) * 4));
    int*   cursor = (int*)(ws + alloc((size_t)NN * 4));
    int*   deg    = (int*)(ws + alloc((size_t)NN * 4));
    int*   bsum   = (int*)(ws + alloc(4096));
    int*   eflag  = (int*)(ws + alloc(256));
    int2*  pack   = (int2*)(ws + alloc((size_t)EE * 8));
    float* buf0   = (float*)(ws + alloc((size_t)NN * DH * 4));
    float* buf1   = (float*)(ws + alloc((size_t)NN * DH * 4));
    (void)ws_size;

    // ---- CSR build ----
    k_detect<<<1, 256, 0, stream>>>(ei64, eflag);
    hipMemsetAsync(deg, 0, (size_t)NN * 4, stream);
    k_deg<<<(EE + 1023) / 1024, 256, 0, stream>>>(ei32, ei64, eflag, deg);
    k_scan_part<<<SCAN_NB, 256, 0, stream>>>(deg, bsum);
    k_scan_mid<<<1, 128, 0, stream>>>(bsum, rowptr);
    k_scan_fin<<<SCAN_NB, 256, 0, stream>>>(deg, bsum, rowptr);
    hipMemcpyAsync(cursor, rowptr, (size_t)NN * 4, hipMemcpyDeviceToDevice, stream);
    k_scatter<<<(EE + 1023) / 1024, 256, 0, stream>>>(ei32, ei64, eflag, ew, cursor, pack);

    // ---- layer 1 ----
    k_gemm128<<<(NN + 63) / 64, 256, 0, stream>>>(x, W1, buf0);
    k_agg128<<<(NN + 7) / 8, 256, 0, stream>>>(buf0, rowptr, pack, b1, buf1);
    // ---- layer 2 ----
    k_gemm128<<<(NN + 63) / 64, 256, 0, stream>>>(buf1, W2, buf0);
    k_agg128<<<(NN + 7) / 8, 256, 0, stream>>>(buf0, rowptr, pack, b2, buf1);
    // ---- layer 3 + log_softmax ----
    k_gemm40<<<NN / 32, 256, 0, stream>>>(buf1, W3, buf0);
    k_agg40_lsm<<<NN / 4, 256, 0, stream>>>(buf0, rowptr, pack, b3, out);
}

// Round 9
// 623.956 us; speedup vs baseline: 1.2087x; 1.1573x over previous
//
#include <hip/hip_runtime.h>
#include <hip/hip_bf16.h>
#include <hip/hip_fp16.h>
#include <math.h>

#define NN 100000      // nodes
#define EE 1600000     // edges
#define DH 128         // hidden dim
#define DO 40          // out dim
#define SCAN_NB ((NN + 1023) / 1024)   // 98 scan blocks

// ---------------------------------------------------------------------------
// Edge-index dtype detection (immune to int32-vs-int64 delivery).
// ---------------------------------------------------------------------------
__global__ void k_detect(const long long* __restrict__ e64, int* __restrict__ flag) {
    __shared__ int sbad;
    if (threadIdx.x == 0) sbad = 0;
    __syncthreads();
    int bad = 0;
    for (int i = threadIdx.x; i < 4096; i += 256) {
        long long v = e64[i];
        if (v < 0 || v >= NN) bad = 1;
    }
    if (__any(bad) && (threadIdx.x & 63) == 0) sbad = 1;
    __syncthreads();
    if (threadIdx.x == 0) flag[0] = sbad ? 0 : 1;   // 1 => int64 layout
}

__device__ __forceinline__ int edge_at(const int* ei32, const long long* ei64,
                                       int is64, size_t idx) {
    return is64 ? (int)ei64[idx] : ei32[idx];
}

// ---------------------------------------------------------------------------
// CSR build: degree histogram -> exclusive scan -> scatter
// ---------------------------------------------------------------------------
__global__ void k_deg(const int* __restrict__ ei32, const long long* __restrict__ ei64,
                      const int* __restrict__ flag, int* __restrict__ deg) {
    int is64 = flag[0];
    int e0 = blockIdx.x * 1024 + threadIdx.x;
    #pragma unroll
    for (int i = 0; i < 4; ++i) {
        int e = e0 + i * 256;
        if (e < EE) {
            int d = edge_at(ei32, ei64, is64, (size_t)EE + e);
            if (d >= 0 && d < NN)
                atomicAdd(&deg[d], 1);
        }
    }
}

__global__ void k_scan_part(const int* __restrict__ deg, int* __restrict__ bsum) {
    int tid = threadIdx.x;
    int base = blockIdx.x * 1024;
    int s = 0;
    #pragma unroll
    for (int i = 0; i < 4; ++i) {
        int idx = base + i * 256 + tid;
        if (idx < NN) s += deg[idx];
    }
    #pragma unroll
    for (int off = 32; off > 0; off >>= 1) s += __shfl_down(s, off, 64);
    __shared__ int ws[4];
    int lane = tid & 63, w = tid >> 6;
    if (lane == 0) ws[w] = s;
    __syncthreads();
    if (tid == 0) bsum[blockIdx.x] = ws[0] + ws[1] + ws[2] + ws[3];
}

// parallel 98-element exclusive scan
__global__ void k_scan_mid(int* __restrict__ bsum, int* __restrict__ rowptr) {
    int tid = threadIdx.x;                  // 128 threads
    int v = (tid < SCAN_NB) ? bsum[tid] : 0;
    int lane = tid & 63, w = tid >> 6;
    int incl = v;
    #pragma unroll
    for (int off = 1; off < 64; off <<= 1) {
        int t = __shfl_up(incl, off, 64);
        if (lane >= off) incl += t;
    }
    __shared__ int ws[2];
    if (lane == 63) ws[w] = incl;
    __syncthreads();
    if (w == 1) incl += ws[0];
    if (tid < SCAN_NB) bsum[tid] = incl - v;          // exclusive
    if (tid == SCAN_NB - 1) rowptr[NN] = incl;        // total == EE
}

__global__ void k_scan_fin(const int* __restrict__ deg, const int* __restrict__ bsum,
                           int* __restrict__ rowptr) {
    int tid = threadIdx.x;
    int base = blockIdx.x * 1024 + tid * 4;
    int v[4];
    #pragma unroll
    for (int j = 0; j < 4; ++j) v[j] = (base + j < NN) ? deg[base + j] : 0;
    int tsum = v[0] + v[1] + v[2] + v[3];
    int lane = tid & 63, w = tid >> 6;
    int incl = tsum;
    #pragma unroll
    for (int off = 1; off < 64; off <<= 1) {
        int t = __shfl_up(incl, off, 64);
        if (lane >= off) incl += t;
    }
    __shared__ int wsum[4];
    __shared__ int woff[4];
    if (lane == 63) wsum[w] = incl;
    __syncthreads();
    if (tid == 0) {
        int r = 0;
        #pragma unroll
        for (int i = 0; i < 4; ++i) { int t = wsum[i]; woff[i] = r; r += t; }
    }
    __syncthreads();
    int run = incl - tsum + woff[w] + bsum[blockIdx.x];
    #pragma unroll
    for (int j = 0; j < 4; ++j) {
        if (base + j < NN) rowptr[base + j] = run;
        run += v[j];
    }
}

// Scatter: 4 edges/thread, packed (src,wgt) int2 stores.
__global__ void k_scatter(const int* __restrict__ ei32, const long long* __restrict__ ei64,
                          const int* __restrict__ flag, const float* __restrict__ ew,
                          int* __restrict__ cursor, int2* __restrict__ pack) {
    int is64 = flag[0];
    int e0 = blockIdx.x * 1024 + threadIdx.x;
    int s[4], d[4];
    float w[4];
    bool val[4];
    #pragma unroll
    for (int i = 0; i < 4; ++i) {
        int e = e0 + i * 256;
        val[i] = (e < EE);
        if (val[i]) {
            s[i] = edge_at(ei32, ei64, is64, (size_t)e);
            d[i] = edge_at(ei32, ei64, is64, (size_t)EE + e);
            w[i] = ew[e];
            if (d[i] < 0 || d[i] >= NN) val[i] = false;
        }
    }
    int pos[4];
    #pragma unroll
    for (int i = 0; i < 4; ++i)
        if (val[i]) pos[i] = atomicAdd(&cursor[d[i]], 1);
    #pragma unroll
    for (int i = 0; i < 4; ++i)
        if (val[i] && pos[i] >= 0 && pos[i] < EE) {
            int sc = (s[i] >= 0 && s[i] < NN) ? s[i] : 0;
            pack[pos[i]] = make_int2(sc, __float_as_int(w[i]));
        }
}

// ---------------------------------------------------------------------------
// GEMM  [N,128] x [128,128] -> [N,128] fp16-out (fp32 accumulate).
// The output is only consumed by the gather kernel -> fp16 halves its bytes.
// ---------------------------------------------------------------------------
__global__ __launch_bounds__(256, 2) void k_gemm128(const float* __restrict__ X,
                                                    const float* __restrict__ W,
                                                    __half* __restrict__ out) {
    __shared__ float Wlds[128 * 128];   // 64 KB
    __shared__ float xs[32 * 128];      // 16 KB
    int tid = threadIdx.x;
    const float4* W4 = (const float4*)W;
    float4* Wl4 = (float4*)Wlds;
    #pragma unroll
    for (int i = 0; i < 16; ++i) Wl4[tid + i * 256] = W4[tid + i * 256];

    int cg = tid & 31;
    int rh = tid >> 5;

    for (int pass = 0; pass < 2; ++pass) {
        int rbase = blockIdx.x * 64 + pass * 32;
        if (rbase >= NN) break;
        __syncthreads();
        const float4* X4 = (const float4*)(X + (size_t)rbase * 128);
        float4* xs4 = (float4*)xs;
        #pragma unroll
        for (int i = 0; i < 4; ++i) xs4[tid + i * 256] = X4[tid + i * 256];
        __syncthreads();

        float acc[4][4];
        #pragma unroll
        for (int j = 0; j < 4; ++j)
            #pragma unroll
            for (int q = 0; q < 4; ++q) acc[j][q] = 0.0f;

        const float4* Wl4c = (const float4*)Wlds;
        #pragma unroll 8
        for (int k = 0; k < 128; ++k) {
            float4 wv = Wl4c[k * 32 + cg];
            #pragma unroll
            for (int j = 0; j < 4; ++j) {
                float xk = xs[(rh * 4 + j) * 128 + k];
                acc[j][0] += xk * wv.x;
                acc[j][1] += xk * wv.y;
                acc[j][2] += xk * wv.z;
                acc[j][3] += xk * wv.w;
            }
        }
        #pragma unroll
        for (int j = 0; j < 4; ++j) {
            int row = rbase + rh * 4 + j;
            __half2 lo = __floats2half2_rn(acc[j][0], acc[j][1]);
            __half2 hi = __floats2half2_rn(acc[j][2], acc[j][3]);
            uint2 st;
            st.x = *reinterpret_cast<unsigned int*>(&lo);
            st.y = *reinterpret_cast<unsigned int*>(&hi);
            ((uint2*)(out + (size_t)row * 128))[cg] = st;
        }
    }
}

// ---------------------------------------------------------------------------
// GEMM  [N,128] x [128,40] -> [N,40] fp16-out
// ---------------------------------------------------------------------------
__global__ __launch_bounds__(256) void k_gemm40(const float* __restrict__ X,
                                                const float* __restrict__ W,
                                                __half* __restrict__ out) {
    __shared__ float Wlds[128 * 40];    // 20 KB
    int tid = threadIdx.x;
    const float4* W4 = (const float4*)W;
    float4* Wl4 = (float4*)Wlds;
    #pragma unroll
    for (int i = 0; i < 5; ++i) Wl4[tid + i * 256] = W4[tid + i * 256];
    __syncthreads();

    int lane = tid & 63;
    int wv = tid >> 6;
    int r8 = lane >> 3;
    int cq = lane & 7;
    int row = blockIdx.x * 32 + wv * 8 + r8;   // NN % 32 == 0
    const float4* x4 = (const float4*)(X + (size_t)row * 128);

    float acc[5] = {0, 0, 0, 0, 0};
    #pragma unroll 4
    for (int k4 = 0; k4 < 32; ++k4) {
        float4 xv = x4[k4];
        float xk[4] = {xv.x, xv.y, xv.z, xv.w};
        #pragma unroll
        for (int kk = 0; kk < 4; ++kk) {
            int k = k4 * 4 + kk;
            #pragma unroll
            for (int j = 0; j < 5; ++j)
                acc[j] += xk[kk] * Wlds[k * 40 + cq * 5 + j];
        }
    }
    #pragma unroll
    for (int j = 0; j < 5; ++j)
        out[(size_t)row * 40 + cq * 5 + j] = __float2half(acc[j]);
}

// ---------------------------------------------------------------------------
// CSR pull aggregation, D=128, fp16 gather: 32 lanes/node, 8B (4 halves)/lane.
// BW-bound kernel (r8: duration tracks FETCH bytes) -> halve the bytes.
// fp32 accumulate + bias + ReLU, fp32 out (streamed by next GEMM).
// ---------------------------------------------------------------------------
__global__ __launch_bounds__(256) void k_agg128(const __half* __restrict__ h,
                                                const int* __restrict__ rowptr,
                                                const int2* __restrict__ pack,
                                                const float* __restrict__ bias,
                                                float* __restrict__ out) {
    int node = (blockIdx.x * 256 + threadIdx.x) >> 5;   // 32-lane group per node
    if (node >= NN) return;
    int lane = threadIdx.x & 31;                        // 4-half slot within row
    int beg = rowptr[node], end = rowptr[node + 1];
    float4 acc = make_float4(0.f, 0.f, 0.f, 0.f);
    int e = beg;
    for (; e + 3 < end; e += 4) {
        int2 p0 = pack[e],     p1 = pack[e + 1];
        int2 p2 = pack[e + 2], p3 = pack[e + 3];
        float w0 = __int_as_float(p0.y), w1 = __int_as_float(p1.y);
        float w2 = __int_as_float(p2.y), w3 = __int_as_float(p3.y);
        uint2 r0 = *((const uint2*)(h + (size_t)p0.x * 128) + lane);
        uint2 r1 = *((const uint2*)(h + (size_t)p1.x * 128) + lane);
        uint2 r2 = *((const uint2*)(h + (size_t)p2.x * 128) + lane);
        uint2 r3 = *((const uint2*)(h + (size_t)p3.x * 128) + lane);
        float2 a0 = __half22float2(*reinterpret_cast<__half2*>(&r0.x));
        float2 b0 = __half22float2(*reinterpret_cast<__half2*>(&r0.y));
        float2 a1 = __half22float2(*reinterpret_cast<__half2*>(&r1.x));
        float2 b1 = __half22float2(*reinterpret_cast<__half2*>(&r1.y));
        float2 a2 = __half22float2(*reinterpret_cast<__half2*>(&r2.x));
        float2 b2 = __half22float2(*reinterpret_cast<__half2*>(&r2.y));
        float2 a3 = __half22float2(*reinterpret_cast<__half2*>(&r3.x));
        float2 b3 = __half22float2(*reinterpret_cast<__half2*>(&r3.y));
        acc.x += w0 * a0.x + w1 * a1.x + w2 * a2.x + w3 * a3.x;
        acc.y += w0 * a0.y + w1 * a1.y + w2 * a2.y + w3 * a3.y;
        acc.z += w0 * b0.x + w1 * b1.x + w2 * b2.x + w3 * b3.x;
        acc.w += w0 * b0.y + w1 * b1.y + w2 * b2.y + w3 * b3.y;
    }
    for (; e < end; ++e) {
        int2 p0 = pack[e];
        float w0 = __int_as_float(p0.y);
        uint2 r0 = *((const uint2*)(h + (size_t)p0.x * 128) + lane);
        float2 a0 = __half22float2(*reinterpret_cast<__half2*>(&r0.x));
        float2 b0 = __half22float2(*reinterpret_cast<__half2*>(&r0.y));
        acc.x += w0 * a0.x;
        acc.y += w0 * a0.y;
        acc.z += w0 * b0.x;
        acc.w += w0 * b0.y;
    }
    float4 b = ((const float4*)bias)[lane];
    acc.x = fmaxf(acc.x + b.x, 0.f);
    acc.y = fmaxf(acc.y + b.y, 0.f);
    acc.z = fmaxf(acc.z + b.z, 0.f);
    acc.w = fmaxf(acc.w + b.w, 0.f);
    *((float4*)(out + (size_t)node * 128) + lane) = acc;
}

// ---------------------------------------------------------------------------
// CSR pull aggregation D=40 fp16 gather + bias + log_softmax. One wave/node.
// ---------------------------------------------------------------------------
__global__ __launch_bounds__(256) void k_agg40_lsm(const __half* __restrict__ h,
                                                   const int* __restrict__ rowptr,
                                                   const int2* __restrict__ pack,
                                                   const float* __restrict__ bias,
                                                   float* __restrict__ out) {
    int node = (blockIdx.x * 256 + threadIdx.x) >> 6;
    if (node >= NN) return;
    int lane = threadIdx.x & 63;
    bool act = lane < DO;
    int ln = act ? lane : 0;                 // keep inactive lanes in-bounds
    int beg = rowptr[node], end = rowptr[node + 1];
    float acc = 0.f;
    int e = beg;
    for (; e + 3 < end; e += 4) {
        int2 p0 = pack[e],     p1 = pack[e + 1];
        int2 p2 = pack[e + 2], p3 = pack[e + 3];
        float v0 = __half2float(h[(size_t)p0.x * DO + ln]);
        float v1 = __half2float(h[(size_t)p1.x * DO + ln]);
        float v2 = __half2float(h[(size_t)p2.x * DO + ln]);
        float v3 = __half2float(h[(size_t)p3.x * DO + ln]);
        acc += __int_as_float(p0.y) * v0 + __int_as_float(p1.y) * v1
             + __int_as_float(p2.y) * v2 + __int_as_float(p3.y) * v3;
    }
    for (; e < end; ++e) {
        int2 p0 = pack[e];
        acc += __int_as_float(p0.y) * __half2float(h[(size_t)p0.x * DO + ln]);
    }
    acc += bias[ln];

    float m = act ? acc : -INFINITY;
    #pragma unroll
    for (int off = 32; off > 0; off >>= 1) m = fmaxf(m, __shfl_xor(m, off, 64));
    float ex = act ? expf(acc - m) : 0.f;
    float s = ex;
    #pragma unroll
    for (int off = 32; off > 0; off >>= 1) s += __shfl_xor(s, off, 64);
    float res = acc - m - logf(s);
    if (act) out[(size_t)node * DO + lane] = res;
}

// ---------------------------------------------------------------------------
static inline size_t align_up(size_t x, size_t a) { return (x + a - 1) & ~(a - 1); }

extern "C" void kernel_launch(void* const* d_in, const int* in_sizes, int n_in,
                              void* d_out, int out_size, void* d_ws, size_t ws_size,
                              hipStream_t stream) {
    const float*     x    = (const float*)d_in[0];
    const int*       ei32 = (const int*)d_in[1];
    const long long* ei64 = (const long long*)d_in[1];
    const float*     ew   = (const float*)d_in[2];
    const float*     W1   = (const float*)d_in[3];
    const float*     b1   = (const float*)d_in[4];
    const float*     W2   = (const float*)d_in[5];
    const float*     b2   = (const float*)d_in[6];
    const float*     W3   = (const float*)d_in[7];
    const float*     b3   = (const float*)d_in[8];
    float* out = (float*)d_out;

    char* ws = (char*)d_ws;
    size_t off = 0;
    auto alloc = [&](size_t bytes) { size_t o = off; off = align_up(off + bytes, 256); return o; };
    int*    rowptr = (int*)(ws + alloc((size_t)(NN + 1) * 4));
    int*    cursor = (int*)(ws + alloc((size_t)NN * 4));
    int*    deg    = (int*)(ws + alloc((size_t)NN * 4));
    int*    bsum   = (int*)(ws + alloc(4096));
    int*    eflag  = (int*)(ws + alloc(256));
    int2*   pack   = (int2*)(ws + alloc((size_t)EE * 8));
    __half* hbuf   = (__half*)(ws + alloc((size_t)NN * DH * 2));  // fp16 activations
    float*  fbuf   = (float*)(ws + alloc((size_t)NN * DH * 4));   // fp32 agg output
    (void)ws_size;

    // ---- CSR build ----
    k_detect<<<1, 256, 0, stream>>>(ei64, eflag);
    hipMemsetAsync(deg, 0, (size_t)NN * 4, stream);
    k_deg<<<(EE + 1023) / 1024, 256, 0, stream>>>(ei32, ei64, eflag, deg);
    k_scan_part<<<SCAN_NB, 256, 0, stream>>>(deg, bsum);
    k_scan_mid<<<1, 128, 0, stream>>>(bsum, rowptr);
    k_scan_fin<<<SCAN_NB, 256, 0, stream>>>(deg, bsum, rowptr);
    hipMemcpyAsync(cursor, rowptr, (size_t)NN * 4, hipMemcpyDeviceToDevice, stream);
    k_scatter<<<(EE + 1023) / 1024, 256, 0, stream>>>(ei32, ei64, eflag, ew, cursor, pack);

    // ---- layer 1 ----
    k_gemm128<<<(NN + 63) / 64, 256, 0, stream>>>(x, W1, hbuf);
    k_agg128<<<(NN + 7) / 8, 256, 0, stream>>>(hbuf, rowptr, pack, b1, fbuf);
    // ---- layer 2 ----
    k_gemm128<<<(NN + 63) / 64, 256, 0, stream>>>(fbuf, W2, hbuf);
    k_agg128<<<(NN + 7) / 8, 256, 0, stream>>>(hbuf, rowptr, pack, b2, fbuf);
    // ---- layer 3 + log_softmax ----
    k_gemm40<<<NN / 32, 256, 0, stream>>>(fbuf, W3, hbuf);
    k_agg40_lsm<<<NN / 4, 256, 0, stream>>>(hbuf, rowptr, pack, b3, out);
}

// Round 10
// 550.265 us; speedup vs baseline: 1.3706x; 1.1339x over previous
//
#include <hip/hip_runtime.h>
#include <hip/hip_bf16.h>
#include <hip/hip_fp16.h>
#include <math.h>

#define NN 100000      // nodes
#define EE 1600000     // edges
#define DH 128         // hidden dim
#define DO 40          // out dim
#define SCAN_NB ((NN + 1023) / 1024)   // 98 scan blocks

// ---------------------------------------------------------------------------
// Edge-index dtype detection (immune to int32-vs-int64 delivery).
// ---------------------------------------------------------------------------
__global__ void k_detect(const long long* __restrict__ e64, int* __restrict__ flag) {
    __shared__ int sbad;
    if (threadIdx.x == 0) sbad = 0;
    __syncthreads();
    int bad = 0;
    for (int i = threadIdx.x; i < 4096; i += 256) {
        long long v = e64[i];
        if (v < 0 || v >= NN) bad = 1;
    }
    if (__any(bad) && (threadIdx.x & 63) == 0) sbad = 1;
    __syncthreads();
    if (threadIdx.x == 0) flag[0] = sbad ? 0 : 1;   // 1 => int64 layout
}

__device__ __forceinline__ int edge_at(const int* ei32, const long long* ei64,
                                       int is64, size_t idx) {
    return is64 ? (int)ei64[idx] : ei32[idx];
}

// ---------------------------------------------------------------------------
// CSR build, pass 1: degree histogram with RETURNING atomic -> rank[e].
// The returned old count is this edge's unique slot within its destination,
// so pass 2 (scatter) needs NO atomic (r9: scatter was atomic-chain-bound).
// rank[] store is indexed by e -> coalesced.
// ---------------------------------------------------------------------------
__global__ void k_deg(const int* __restrict__ ei32, const long long* __restrict__ ei64,
                      const int* __restrict__ flag, int* __restrict__ deg,
                      int* __restrict__ rank) {
    int is64 = flag[0];
    int e0 = blockIdx.x * 1024 + threadIdx.x;
    int d[4];
    bool val[4];
    #pragma unroll
    for (int i = 0; i < 4; ++i) {
        int e = e0 + i * 256;
        val[i] = (e < EE);
        if (val[i]) {
            d[i] = edge_at(ei32, ei64, is64, (size_t)EE + e);
            if (d[i] < 0 || d[i] >= NN) val[i] = false;
        }
    }
    int r[4];
    #pragma unroll
    for (int i = 0; i < 4; ++i)
        if (val[i]) r[i] = atomicAdd(&deg[d[i]], 1);   // 4 independent chains in flight
    #pragma unroll
    for (int i = 0; i < 4; ++i) {
        int e = e0 + i * 256;
        if (e < EE) rank[e] = val[i] ? r[i] : 0;       // coalesced
    }
}

__global__ void k_scan_part(const int* __restrict__ deg, int* __restrict__ bsum) {
    int tid = threadIdx.x;
    int base = blockIdx.x * 1024;
    int s = 0;
    #pragma unroll
    for (int i = 0; i < 4; ++i) {
        int idx = base + i * 256 + tid;
        if (idx < NN) s += deg[idx];
    }
    #pragma unroll
    for (int off = 32; off > 0; off >>= 1) s += __shfl_down(s, off, 64);
    __shared__ int ws[4];
    int lane = tid & 63, w = tid >> 6;
    if (lane == 0) ws[w] = s;
    __syncthreads();
    if (tid == 0) bsum[blockIdx.x] = ws[0] + ws[1] + ws[2] + ws[3];
}

// parallel 98-element exclusive scan
__global__ void k_scan_mid(int* __restrict__ bsum, int* __restrict__ rowptr) {
    int tid = threadIdx.x;                  // 128 threads
    int v = (tid < SCAN_NB) ? bsum[tid] : 0;
    int lane = tid & 63, w = tid >> 6;
    int incl = v;
    #pragma unroll
    for (int off = 1; off < 64; off <<= 1) {
        int t = __shfl_up(incl, off, 64);
        if (lane >= off) incl += t;
    }
    __shared__ int ws[2];
    if (lane == 63) ws[w] = incl;
    __syncthreads();
    if (w == 1) incl += ws[0];
    if (tid < SCAN_NB) bsum[tid] = incl - v;          // exclusive
    if (tid == SCAN_NB - 1) rowptr[NN] = incl;        // total == EE
}

__global__ void k_scan_fin(const int* __restrict__ deg, const int* __restrict__ bsum,
                           int* __restrict__ rowptr) {
    int tid = threadIdx.x;
    int base = blockIdx.x * 1024 + tid * 4;
    int v[4];
    #pragma unroll
    for (int j = 0; j < 4; ++j) v[j] = (base + j < NN) ? deg[base + j] : 0;
    int tsum = v[0] + v[1] + v[2] + v[3];
    int lane = tid & 63, w = tid >> 6;
    int incl = tsum;
    #pragma unroll
    for (int off = 1; off < 64; off <<= 1) {
        int t = __shfl_up(incl, off, 64);
        if (lane >= off) incl += t;
    }
    __shared__ int wsum[4];
    __shared__ int woff[4];
    if (lane == 63) wsum[w] = incl;
    __syncthreads();
    if (tid == 0) {
        int r = 0;
        #pragma unroll
        for (int i = 0; i < 4; ++i) { int t = wsum[i]; woff[i] = r; r += t; }
    }
    __syncthreads();
    int run = incl - tsum + woff[w] + bsum[blockIdx.x];
    #pragma unroll
    for (int j = 0; j < 4; ++j) {
        if (base + j < NN) rowptr[base + j] = run;
        run += v[j];
    }
}

// CSR build, pass 2: atomic-free scatter. pos = rowptr[d] + rank[e].
__global__ void k_scatter(const int* __restrict__ ei32, const long long* __restrict__ ei64,
                          const int* __restrict__ flag, const float* __restrict__ ew,
                          const int* __restrict__ rowptr, const int* __restrict__ rank,
                          int2* __restrict__ pack) {
    int is64 = flag[0];
    int e0 = blockIdx.x * 1024 + threadIdx.x;
    #pragma unroll
    for (int i = 0; i < 4; ++i) {
        int e = e0 + i * 256;
        if (e < EE) {
            int s = edge_at(ei32, ei64, is64, (size_t)e);
            int d = edge_at(ei32, ei64, is64, (size_t)EE + e);
            if (d < 0 || d >= NN) continue;
            int pos = rowptr[d] + rank[e];
            if (pos < 0 || pos >= EE) continue;
            int sc = (s >= 0 && s < NN) ? s : 0;
            pack[pos] = make_int2(sc, __float_as_int(ew[e]));
        }
    }
}

// ---------------------------------------------------------------------------
// GEMM  [N,128] x [128,128] -> [N,128] fp16-out (fp32 accumulate).
// ---------------------------------------------------------------------------
__global__ __launch_bounds__(256, 2) void k_gemm128(const float* __restrict__ X,
                                                    const float* __restrict__ W,
                                                    __half* __restrict__ out) {
    __shared__ float Wlds[128 * 128];   // 64 KB
    __shared__ float xs[32 * 128];      // 16 KB
    int tid = threadIdx.x;
    const float4* W4 = (const float4*)W;
    float4* Wl4 = (float4*)Wlds;
    #pragma unroll
    for (int i = 0; i < 16; ++i) Wl4[tid + i * 256] = W4[tid + i * 256];

    int cg = tid & 31;
    int rh = tid >> 5;

    for (int pass = 0; pass < 2; ++pass) {
        int rbase = blockIdx.x * 64 + pass * 32;
        if (rbase >= NN) break;
        __syncthreads();
        const float4* X4 = (const float4*)(X + (size_t)rbase * 128);
        float4* xs4 = (float4*)xs;
        #pragma unroll
        for (int i = 0; i < 4; ++i) xs4[tid + i * 256] = X4[tid + i * 256];
        __syncthreads();

        float acc[4][4];
        #pragma unroll
        for (int j = 0; j < 4; ++j)
            #pragma unroll
            for (int q = 0; q < 4; ++q) acc[j][q] = 0.0f;

        const float4* Wl4c = (const float4*)Wlds;
        #pragma unroll 8
        for (int k = 0; k < 128; ++k) {
            float4 wv = Wl4c[k * 32 + cg];
            #pragma unroll
            for (int j = 0; j < 4; ++j) {
                float xk = xs[(rh * 4 + j) * 128 + k];
                acc[j][0] += xk * wv.x;
                acc[j][1] += xk * wv.y;
                acc[j][2] += xk * wv.z;
                acc[j][3] += xk * wv.w;
            }
        }
        #pragma unroll
        for (int j = 0; j < 4; ++j) {
            int row = rbase + rh * 4 + j;
            __half2 lo = __floats2half2_rn(acc[j][0], acc[j][1]);
            __half2 hi = __floats2half2_rn(acc[j][2], acc[j][3]);
            uint2 st;
            st.x = *reinterpret_cast<unsigned int*>(&lo);
            st.y = *reinterpret_cast<unsigned int*>(&hi);
            ((uint2*)(out + (size_t)row * 128))[cg] = st;
        }
    }
}

// ---------------------------------------------------------------------------
// GEMM  [N,128] x [128,40] -> [N,40] fp16-out
// ---------------------------------------------------------------------------
__global__ __launch_bounds__(256) void k_gemm40(const float* __restrict__ X,
                                                const float* __restrict__ W,
                                                __half* __restrict__ out) {
    __shared__ float Wlds[128 * 40];    // 20 KB
    int tid = threadIdx.x;
    const float4* W4 = (const float4*)W;
    float4* Wl4 = (float4*)Wlds;
    #pragma unroll
    for (int i = 0; i < 5; ++i) Wl4[tid + i * 256] = W4[tid + i * 256];
    __syncthreads();

    int lane = tid & 63;
    int wv = tid >> 6;
    int r8 = lane >> 3;
    int cq = lane & 7;
    int row = blockIdx.x * 32 + wv * 8 + r8;   // NN % 32 == 0
    const float4* x4 = (const float4*)(X + (size_t)row * 128);

    float acc[5] = {0, 0, 0, 0, 0};
    #pragma unroll 4
    for (int k4 = 0; k4 < 32; ++k4) {
        float4 xv = x4[k4];
        float xk[4] = {xv.x, xv.y, xv.z, xv.w};
        #pragma unroll
        for (int kk = 0; kk < 4; ++kk) {
            int k = k4 * 4 + kk;
            #pragma unroll
            for (int j = 0; j < 5; ++j)
                acc[j] += xk[kk] * Wlds[k * 40 + cq * 5 + j];
        }
    }
    #pragma unroll
    for (int j = 0; j < 5; ++j)
        out[(size_t)row * 40 + cq * 5 + j] = __float2half(acc[j]);
}

// ---------------------------------------------------------------------------
// CSR pull aggregation, D=128, fp16 gather: 32 lanes/node, 8B (4 halves)/lane.
// fp32 accumulate + bias + ReLU, fp32 out (streamed by next GEMM).
// ---------------------------------------------------------------------------
__global__ __launch_bounds__(256) void k_agg128(const __half* __restrict__ h,
                                                const int* __restrict__ rowptr,
                                                const int2* __restrict__ pack,
                                                const float* __restrict__ bias,
                                                float* __restrict__ out) {
    int node = (blockIdx.x * 256 + threadIdx.x) >> 5;   // 32-lane group per node
    if (node >= NN) return;
    int lane = threadIdx.x & 31;                        // 4-half slot within row
    int beg = rowptr[node], end = rowptr[node + 1];
    float4 acc = make_float4(0.f, 0.f, 0.f, 0.f);
    int e = beg;
    for (; e + 3 < end; e += 4) {
        int2 p0 = pack[e],     p1 = pack[e + 1];
        int2 p2 = pack[e + 2], p3 = pack[e + 3];
        float w0 = __int_as_float(p0.y), w1 = __int_as_float(p1.y);
        float w2 = __int_as_float(p2.y), w3 = __int_as_float(p3.y);
        uint2 r0 = *((const uint2*)(h + (size_t)p0.x * 128) + lane);
        uint2 r1 = *((const uint2*)(h + (size_t)p1.x * 128) + lane);
        uint2 r2 = *((const uint2*)(h + (size_t)p2.x * 128) + lane);
        uint2 r3 = *((const uint2*)(h + (size_t)p3.x * 128) + lane);
        float2 a0 = __half22float2(*reinterpret_cast<__half2*>(&r0.x));
        float2 b0 = __half22float2(*reinterpret_cast<__half2*>(&r0.y));
        float2 a1 = __half22float2(*reinterpret_cast<__half2*>(&r1.x));
        float2 b1 = __half22float2(*reinterpret_cast<__half2*>(&r1.y));
        float2 a2 = __half22float2(*reinterpret_cast<__half2*>(&r2.x));
        float2 b2 = __half22float2(*reinterpret_cast<__half2*>(&r2.y));
        float2 a3 = __half22float2(*reinterpret_cast<__half2*>(&r3.x));
        float2 b3 = __half22float2(*reinterpret_cast<__half2*>(&r3.y));
        acc.x += w0 * a0.x + w1 * a1.x + w2 * a2.x + w3 * a3.x;
        acc.y += w0 * a0.y + w1 * a1.y + w2 * a2.y + w3 * a3.y;
        acc.z += w0 * b0.x + w1 * b1.x + w2 * b2.x + w3 * b3.x;
        acc.w += w0 * b0.y + w1 * b1.y + w2 * b2.y + w3 * b3.y;
    }
    for (; e < end; ++e) {
        int2 p0 = pack[e];
        float w0 = __int_as_float(p0.y);
        uint2 r0 = *((const uint2*)(h + (size_t)p0.x * 128) + lane);
        float2 a0 = __half22float2(*reinterpret_cast<__half2*>(&r0.x));
        float2 b0 = __half22float2(*reinterpret_cast<__half2*>(&r0.y));
        acc.x += w0 * a0.x;
        acc.y += w0 * a0.y;
        acc.z += w0 * b0.x;
        acc.w += w0 * b0.y;
    }
    float4 b = ((const float4*)bias)[lane];
    acc.x = fmaxf(acc.x + b.x, 0.f);
    acc.y = fmaxf(acc.y + b.y, 0.f);
    acc.z = fmaxf(acc.z + b.z, 0.f);
    acc.w = fmaxf(acc.w + b.w, 0.f);
    *((float4*)(out + (size_t)node * 128) + lane) = acc;
}

// ---------------------------------------------------------------------------
// CSR pull aggregation D=40 fp16 gather + bias + log_softmax. One wave/node.
// ---------------------------------------------------------------------------
__global__ __launch_bounds__(256) void k_agg40_lsm(const __half* __restrict__ h,
                                                   const int* __restrict__ rowptr,
                                                   const int2* __restrict__ pack,
                                                   const float* __restrict__ bias,
                                                   float* __restrict__ out) {
    int node = (blockIdx.x * 256 + threadIdx.x) >> 6;
    if (node >= NN) return;
    int lane = threadIdx.x & 63;
    bool act = lane < DO;
    int ln = act ? lane : 0;                 // keep inactive lanes in-bounds
    int beg = rowptr[node], end = rowptr[node + 1];
    float acc = 0.f;
    int e = beg;
    for (; e + 3 < end; e += 4) {
        int2 p0 = pack[e],     p1 = pack[e + 1];
        int2 p2 = pack[e + 2], p3 = pack[e + 3];
        float v0 = __half2float(h[(size_t)p0.x * DO + ln]);
        float v1 = __half2float(h[(size_t)p1.x * DO + ln]);
        float v2 = __half2float(h[(size_t)p2.x * DO + ln]);
        float v3 = __half2float(h[(size_t)p3.x * DO + ln]);
        acc += __int_as_float(p0.y) * v0 + __int_as_float(p1.y) * v1
             + __int_as_float(p2.y) * v2 + __int_as_float(p3.y) * v3;
    }
    for (; e < end; ++e) {
        int2 p0 = pack[e];
        acc += __int_as_float(p0.y) * __half2float(h[(size_t)p0.x * DO + ln]);
    }
    acc += bias[ln];

    float m = act ? acc : -INFINITY;
    #pragma unroll
    for (int off = 32; off > 0; off >>= 1) m = fmaxf(m, __shfl_xor(m, off, 64));
    float ex = act ? expf(acc - m) : 0.f;
    float s = ex;
    #pragma unroll
    for (int off = 32; off > 0; off >>= 1) s += __shfl_xor(s, off, 64);
    float res = acc - m - logf(s);
    if (act) out[(size_t)node * DO + lane] = res;
}

// ---------------------------------------------------------------------------
static inline size_t align_up(size_t x, size_t a) { return (x + a - 1) & ~(a - 1); }

extern "C" void kernel_launch(void* const* d_in, const int* in_sizes, int n_in,
                              void* d_out, int out_size, void* d_ws, size_t ws_size,
                              hipStream_t stream) {
    const float*     x    = (const float*)d_in[0];
    const int*       ei32 = (const int*)d_in[1];
    const long long* ei64 = (const long long*)d_in[1];
    const float*     ew   = (const float*)d_in[2];
    const float*     W1   = (const float*)d_in[3];
    const float*     b1   = (const float*)d_in[4];
    const float*     W2   = (const float*)d_in[5];
    const float*     b2   = (const float*)d_in[6];
    const float*     W3   = (const float*)d_in[7];
    const float*     b3   = (const float*)d_in[8];
    float* out = (float*)d_out;

    char* ws = (char*)d_ws;
    size_t off = 0;
    auto alloc = [&](size_t bytes) { size_t o = off; off = align_up(off + bytes, 256); return o; };
    int*    rowptr = (int*)(ws + alloc((size_t)(NN + 1) * 4));
    int*    deg    = (int*)(ws + alloc((size_t)NN * 4));
    int*    bsum   = (int*)(ws + alloc(4096));
    int*    eflag  = (int*)(ws + alloc(256));
    int*    rank   = (int*)(ws + alloc((size_t)EE * 4));
    int2*   pack   = (int2*)(ws + alloc((size_t)EE * 8));
    __half* hbuf   = (__half*)(ws + alloc((size_t)NN * DH * 2));  // fp16 activations
    float*  fbuf   = (float*)(ws + alloc((size_t)NN * DH * 4));   // fp32 agg output
    (void)ws_size;

    // ---- CSR build ----
    k_detect<<<1, 256, 0, stream>>>(ei64, eflag);
    hipMemsetAsync(deg, 0, (size_t)NN * 4, stream);
    k_deg<<<(EE + 1023) / 1024, 256, 0, stream>>>(ei32, ei64, eflag, deg, rank);
    k_scan_part<<<SCAN_NB, 256, 0, stream>>>(deg, bsum);
    k_scan_mid<<<1, 128, 0, stream>>>(bsum, rowptr);
    k_scan_fin<<<SCAN_NB, 256, 0, stream>>>(deg, bsum, rowptr);
    k_scatter<<<(EE + 1023) / 1024, 256, 0, stream>>>(ei32, ei64, eflag, ew, rowptr, rank, pack);

    // ---- layer 1 ----
    k_gemm128<<<(NN + 63) / 64, 256, 0, stream>>>(x, W1, hbuf);
    k_agg128<<<(NN + 7) / 8, 256, 0, stream>>>(hbuf, rowptr, pack, b1, fbuf);
    // ---- layer 2 ----
    k_gemm128<<<(NN + 63) / 64, 256, 0, stream>>>(fbuf, W2, hbuf);
    k_agg128<<<(NN + 7) / 8, 256, 0, stream>>>(hbuf, rowptr, pack, b2, fbuf);
    // ---- layer 3 + log_softmax ----
    k_gemm40<<<NN / 32, 256, 0, stream>>>(fbuf, W3, hbuf);
    k_agg40_lsm<<<NN / 4, 256, 0, stream>>>(hbuf, rowptr, pack, b3, out);
}